// Round 5
// baseline (1758.031 us; speedup 1.0000x reference)
//
#include <hip/hip_runtime.h>
#include <hip/hip_bf16.h>

// ============================================================================
// RecurrentDecoder v5: 66-block persistent cooperative kernel, resident data.
// v4 -> v5: grid barrier release is now a per-block MAILBOX BROADCAST.
//   v4's single shared `gen` word was hammered by 66 spinning RMWs; same-
//   address RMWs serialize at the coherence point, costing ~10us/barrier.
//   Now: arrival via 8-leaf tree (unchanged), release via 66 private
//   mailbox stores; each block RMW-polls only its own line. Generation is
//   tracked in a register (every block passes every barrier).
//
//  - att blocks 0..31 (one per batch b): alignment slice in LDS (133 KB),
//    W_att^T columns in VGPRs, 512 threads, split passes.
//  - GRU blocks 32..63 (16-col slice of D each): W_hh/W_ih fragments in VGPRs.
//  - mel blocks 64..65: W_mel/gate fragments resident; works on step s-1.
//  Per step: X[att(s) | gh(s) | mel(s-1)]  bar  Y[gi(s)+GRU pointwise]  bar
// ============================================================================

#define LOG2E 1.4426950408889634f
#define BAR_MAGIC 0x13572468u
#define SMEM_BYTES 146432

typedef __attribute__((ext_vector_type(8))) short bf8;
typedef __attribute__((ext_vector_type(4))) float f32x4;

#if __has_builtin(__builtin_amdgcn_exp2f)
#define EX2(x) __builtin_amdgcn_exp2f(x)
#else
#define EX2(x) exp2f(x)
#endif

#define MFMA16(a, b, c) __builtin_amdgcn_mfma_f32_16x16x32_bf16(a, b, c, 0, 0, 0)

struct Params {
  const float* dec;    // [64][32][256]
  const float* ali;    // [256][32][256]
  const float* watt;   // [256][512]
  const float* wih;    // [1536][512]
  const float* whh;    // [1536][512]
  const float* wmel;   // [80][768]
  const float* bmel;   // [80]
  const float* wgate;  // [768]
  const float* bgate;  // [1]
  float* out;          // mel 32*80*64 then gate 32*64
  unsigned* bar;       // [0]=magic [16]=root [32+16i]=leaf i [160+16j]=mbox j
  __hip_bfloat16* wihb;    // [1536][512]
  __hip_bfloat16* whhb;    // [1536][512]
  __hip_bfloat16* wmelgb;  // [96][768] rows0..79=Wmel,80=Wgate,81..95=0
  __hip_bfloat16* seqb;    // [64][32][256] shifted dec inputs
  __hip_bfloat16* hbf;     // [2][32][512]
  __hip_bfloat16* ctxb;    // [2][32][256]
  unsigned* wattp;         // [256][256]: kp-major packed bf16 pairs of W_att[e]
  float* hf;               // [32][512]
};

__device__ __forceinline__ bf8 ldfrag(const __hip_bfloat16* p) {
  return *(const bf8*)p;
}
__device__ __forceinline__ float sigm(float x) {
  return 1.0f / (1.0f + EX2(-x * LOG2E));
}
__device__ __forceinline__ float tanhfast(float x) {
  x = fminf(fmaxf(x, -15.0f), 15.0f);
  float e = EX2(x * (2.0f * LOG2E));
  return (e - 1.0f) / (e + 1.0f);
}
__device__ __forceinline__ float btof(unsigned short v) {
  return __uint_as_float(((unsigned)v) << 16);
}
__device__ __forceinline__ unsigned short f2bfbits(float x) {
  __hip_bfloat16 h = __float2bfloat16(x);
  return *(unsigned short*)&h;
}
__device__ __forceinline__ unsigned crd(unsigned* p) {
  return __hip_atomic_fetch_add(p, 0u, __ATOMIC_RELAXED, __HIP_MEMORY_SCOPE_AGENT);
}

// Tree-arrive / mailbox-broadcast grid barrier for 66 blocks.
// Arrival: leaf lf=bid&7 (9 members for lf<2, else 8) -> root (8 leaves).
// Release: root-last stores the new generation into 66 private mailboxes;
// each block RMW-polls only its own mailbox (1 poller + 1 writer per line).
__device__ __forceinline__ void gbar(unsigned* bar, int bid, unsigned& myg) {
  __syncthreads();
  ++myg;
  if (threadIdx.x == 0) {
    const int lf = bid & 7;
    unsigned* root = bar + 16;
    unsigned* leaf = bar + 32 + lf * 16;
    unsigned* mbox = bar + 160 + bid * 16;
    const unsigned ltarget = (lf < 2) ? 9u : 8u;
    __builtin_amdgcn_fence(__ATOMIC_RELEASE, "agent");  // publish block's writes
    unsigned o = __hip_atomic_fetch_add(leaf, 1u, __ATOMIC_RELAXED, __HIP_MEMORY_SCOPE_AGENT);
    if ((o + 1u) % ltarget == 0u) {  // leaf-last of this round
      unsigned r = __hip_atomic_fetch_add(root, 1u, __ATOMIC_RELAXED, __HIP_MEMORY_SCOPE_AGENT);
      if (((r + 1u) & 7u) == 0u) {  // root-last: broadcast release
#pragma unroll 6
        for (int j = 0; j < 66; ++j)
          __hip_atomic_store(bar + 160 + j * 16, myg, __ATOMIC_RELAXED,
                             __HIP_MEMORY_SCOPE_AGENT);
      }
    }
    while (crd(mbox) < myg) __builtin_amdgcn_s_sleep(2);
    __builtin_amdgcn_fence(__ATOMIC_ACQUIRE, "agent");  // invalidate stale lines
  }
  __syncthreads();
}

// P0a conversion work for blocks 32..65 (wid in [0, 34*512))
__device__ __forceinline__ void p0a_worker(const Params& p, int wid) {
  for (int i = wid; i < 2252800; i += 17408) {
    if (i < 786432) {
      p.wihb[i] = __float2bfloat16(p.wih[i]);
    } else if (i < 1572864) {
      int j = i - 786432;
      p.whhb[j] = __float2bfloat16(p.whh[j]);
    } else if (i < 2097152) {
      int j = i - 1572864;
      int s = j >> 13;
      p.seqb[j] = (s == 0) ? __float2bfloat16(0.0f) : __float2bfloat16(p.dec[j - 8192]);
    } else if (i < 2170880) {
      int j = i - 2097152;
      int r = j / 768, c = j - r * 768;
      float v = (r < 80) ? p.wmel[j] : ((r == 80) ? p.wgate[c] : 0.0f);
      p.wmelgb[j] = __float2bfloat16(v);
    } else if (i < 2236416) {
      int j = i - 2170880;
      int kp = j >> 8, e = j & 255;
      unsigned lo = f2bfbits(p.watt[e * 512 + 2 * kp]);
      unsigned hi = f2bfbits(p.watt[e * 512 + 2 * kp + 1]);
      p.wattp[j] = lo | (hi << 16);
    } else {
      int j = i - 2236416;
      p.hf[j] = 0.0f;
      p.hbf[j] = __float2bfloat16(0.0f);  // hbf parity 0
    }
  }
}

__global__ void __launch_bounds__(512, 2) rdec_kernel(Params p) {
  const int tid = threadIdx.x;
  const int bid = blockIdx.x;
  extern __shared__ char smem[];
  unsigned myg = 0;  // local barrier generation (all blocks pass all barriers)

  // ---- barrier state init handshake (ws poisoned 0xAA each launch) ----
  if (bid == 0) {
    for (int i = 1 + tid; i < 1216; i += 512)
      __hip_atomic_store(p.bar + i, 0u, __ATOMIC_RELAXED, __HIP_MEMORY_SCOPE_AGENT);
    __syncthreads();
    if (tid == 0) {
      __builtin_amdgcn_fence(__ATOMIC_RELEASE, "agent");
      __hip_atomic_fetch_add(p.bar, BAR_MAGIC, __ATOMIC_RELAXED, __HIP_MEMORY_SCOPE_AGENT);
    }
  }
  if (tid == 0) {
    while (crd(p.bar) < BAR_MAGIC) __builtin_amdgcn_s_sleep(2);
    __builtin_amdgcn_fence(__ATOMIC_ACQUIRE, "agent");
  }
  __syncthreads();

  if (bid < 32) {
    // ============================ ATT path ============================
    const int b = bid;
    unsigned short* alds = (unsigned short*)smem;  // [256][260] bf16
    float* shh = (float*)(smem + 256 * 260 * 2);   // 512
    float* shp = shh + 512;                        // 256
    float* shr = shp + 256;                        // 256
    float* shtw = shr + 256;                       // 256
    float* pA = shtw + 256;                        // 512
    float* pB = pA + 512;
    float* pC = pB + 512;
    float* pD = pC + 512;
    const int e = tid & 255, th = tid >> 8;
    // P0a: ali -> LDS bf16 (this block's batch slice, loaded once)
    for (int i = tid; i < 65536; i += 512) {
      int t = i >> 8, ee = i & 255;
      alds[t * 260 + ee] = f2bfbits(p.ali[t * 8192 + b * 256 + ee]);
    }
    gbar(p.bar, bid, myg);
    // P0b: resident W_att^T column slice (kp-half per th)
    unsigned wr[128];
#pragma unroll
    for (int i = 0; i < 128; ++i) wr[i] = p.wattp[(th * 128 + i) * 256 + e];

    for (int s = 0; s < 64; ++s) {
      shh[tid] = p.hf[b * 512 + tid];
      __syncthreads();
      // proj partial (k-split by th), from registers
      {
        float acc = 0.f;
        const float2* h2 = (const float2*)shh;
#pragma unroll
        for (int i = 0; i < 128; ++i) {
          unsigned w = wr[i];
          float2 hv = h2[th * 128 + i];
          acc = fmaf(__uint_as_float(w << 16), hv.x, acc);
          acc = fmaf(__uint_as_float(w & 0xffff0000u), hv.y, acc);
        }
        pA[th * 256 + e] = acc;
      }
      __syncthreads();
      const float p2 = (pA[e] + pA[256 + e]) * LOG2E;
      if (tid < 256) shp[e] = p2;
      // softmax denominator partial (t-split by th); no max-sub (|arg|<75)
      {
        float d0 = 0.f, d1 = 0.f;
        const int t0 = th * 128;
#pragma unroll 4
        for (int t = t0; t < t0 + 128; t += 2) {
          d0 += EX2(btof(alds[(t + 0) * 260 + e]) * p2);
          d1 += EX2(btof(alds[(t + 1) * 260 + e]) * p2);
        }
        pB[th * 256 + e] = d0 + d1;
      }
      __syncthreads();
      if (tid < 256) shr[e] = 1.0f / (pB[e] + pB[256 + e]);
      __syncthreads();
      // tw partial (e-split by th)
      {
        const int t = tid & 255;
        const ushort4* row = (const ushort4*)(alds + t * 260 + th * 128);
        float acc = 0.f;
#pragma unroll 4
        for (int q = 0; q < 32; ++q) {
          ushort4 v = row[q];
          int eb = th * 128 + q * 4;
          acc += EX2(btof(v.x) * shp[eb + 0]) * shr[eb + 0];
          acc += EX2(btof(v.y) * shp[eb + 1]) * shr[eb + 1];
          acc += EX2(btof(v.z) * shp[eb + 2]) * shr[eb + 2];
          acc += EX2(btof(v.w) * shp[eb + 3]) * shr[eb + 3];
        }
        pC[th * 256 + t] = acc;
      }
      __syncthreads();
      if (tid < 256) shtw[tid] = pC[tid] + pC[256 + tid];
      __syncthreads();
      // ctx partial (t-split by th)
      {
        float c0 = 0.f, c1 = 0.f;
        const int t0 = th * 128;
#pragma unroll 4
        for (int t = t0; t < t0 + 128; t += 2) {
          c0 += shtw[t + 0] * btof(alds[(t + 0) * 260 + e]);
          c1 += shtw[t + 1] * btof(alds[(t + 1) * 260 + e]);
        }
        pD[th * 256 + e] = c0 + c1;
      }
      __syncthreads();
      if (tid < 256)
        p.ctxb[(s & 1) * 8192 + b * 256 + e] = __float2bfloat16(pD[e] + pD[256 + e]);
      gbar(p.bar, bid, myg);  // end X
      gbar(p.bar, bid, myg);  // end Y (idle)
    }
  } else if (bid < 64) {
    // ============================ GRU path ============================
    const int dt = bid - 32;  // dcol tile: d in [dt*16, dt*16+16)
    const int wv = tid >> 6;
    const bool act = wv < 6;
    const int l = tid & 63, lm = l & 15, lq = l >> 4;
    const int g = wv % 3, mt = wv / 3;  // gate, batch-half
    const int am = mt * 16 + lm;
    const int brow = g * 512 + dt * 16 + lm;
    float* pw = (float*)smem;  // [8][16][17] f32
    p0a_worker(p, (bid - 32) * 512 + tid);
    gbar(p.bar, bid, myg);
    // P0b: resident B-fragments (W_hh K=512, W_ih dec K=256, W_ih ctx K=256)
    bf8 WH[16], WD[8], WC[8];
    if (act) {
#pragma unroll
      for (int kt = 0; kt < 16; ++kt) WH[kt] = ldfrag(p.whhb + brow * 512 + kt * 32 + lq * 8);
#pragma unroll
      for (int kt = 0; kt < 8; ++kt) WD[kt] = ldfrag(p.wihb + brow * 512 + kt * 32 + lq * 8);
#pragma unroll
      for (int kt = 0; kt < 8; ++kt) WC[kt] = ldfrag(p.wihb + brow * 512 + 256 + kt * 32 + lq * 8);
    }
    for (int s = 0; s < 64; ++s) {
      // X: gh = h(s) @ W_hh^T (only needs h)
      f32x4 acc = {0.f, 0.f, 0.f, 0.f};
      if (act) {
        const __hip_bfloat16* hb = p.hbf + (s & 1) * 16384;
#pragma unroll
        for (int kt = 0; kt < 16; ++kt) {
          bf8 a = ldfrag(hb + am * 512 + kt * 32 + lq * 8);
          acc = MFMA16(a, WH[kt], acc);
        }
      }
      gbar(p.bar, bid, myg);
      // Y: gi (dec + ctx) and pointwise
      if (act) {
        const __hip_bfloat16* seqp = p.seqb + s * 8192;
        const __hip_bfloat16* ctxp = p.ctxb + (s & 1) * 8192;
        f32x4 gi = {0.f, 0.f, 0.f, 0.f};
#pragma unroll
        for (int kt = 0; kt < 8; ++kt) {
          bf8 a = ldfrag(seqp + am * 256 + kt * 32 + lq * 8);
          gi = MFMA16(a, WD[kt], gi);
        }
#pragma unroll
        for (int kt = 0; kt < 8; ++kt) {
          bf8 a = ldfrag(ctxp + am * 256 + kt * 32 + lq * 8);
          gi = MFMA16(a, WC[kt], gi);
        }
        if (g < 2) {
#pragma unroll
          for (int r = 0; r < 4; ++r) pw[(wv * 16 + lq * 4 + r) * 17 + lm] = acc[r] + gi[r];
        } else {
          // n-gate: keep hidden (hn) and input (inn) parts separate
#pragma unroll
          for (int r = 0; r < 4; ++r) pw[(wv * 16 + lq * 4 + r) * 17 + lm] = acc[r];
#pragma unroll
          for (int r = 0; r < 4; ++r) pw[((6 + mt) * 16 + lq * 4 + r) * 17 + lm] = gi[r];
        }
      }
      __syncthreads();
      // pointwise: 512 threads = 32 b x 16 d
      {
        const int bb = tid >> 4, dl = tid & 15;
        const int mtb = bb >> 4, bl = bb & 15;
        float rg = sigm(pw[((mtb * 3 + 0) * 16 + bl) * 17 + dl]);
        float zg = sigm(pw[((mtb * 3 + 1) * 16 + bl) * 17 + dl]);
        float hn = pw[((mtb * 3 + 2) * 16 + bl) * 17 + dl];
        float inn = pw[((6 + mtb) * 16 + bl) * 17 + dl];
        float nn = tanhfast(fmaf(rg, hn, inn));
        const int d = dt * 16 + dl;
        float ho = p.hf[bb * 512 + d];
        float hnew = fmaxf(0.0f, fmaf(zg, ho - nn, nn));  // relu((1-z)n+z*h)
        p.hf[bb * 512 + d] = hnew;
        p.hbf[((s + 1) & 1) * 16384 + bb * 512 + d] = __float2bfloat16(hnew);
      }
      gbar(p.bar, bid, myg);
    }
  } else {
    // ============================ MEL path ============================
    const int mt = bid - 64;  // batch half
    const int wv = tid >> 6;
    const bool act = wv < 6;
    const int l = tid & 63, lm = l & 15, lq = l >> 4;
    const int nt = wv;
    const int am = mt * 16 + lm, bn = nt * 16 + lm;
    p0a_worker(p, (bid - 32) * 512 + tid);
    gbar(p.bar, bid, myg);
    bf8 WM[24];
    float bias = 0.f;
    if (act) {
#pragma unroll
      for (int kt = 0; kt < 24; ++kt) WM[kt] = ldfrag(p.wmelgb + bn * 768 + kt * 32 + lq * 8);
      bias = (bn < 80) ? p.bmel[bn] : ((bn == 80) ? p.bgate[0] : 0.f);
    }
    for (int s = 0; s < 64; ++s) {
      if (s >= 1 && act) {
        const int tau = s - 1;
        const __hip_bfloat16* ctxp = p.ctxb + (tau & 1) * 8192;
        const __hip_bfloat16* hb = p.hbf + ((tau + 1) & 1) * 16384;
        f32x4 acc = {0.f, 0.f, 0.f, 0.f};
#pragma unroll
        for (int kt = 0; kt < 24; ++kt) {
          bf8 a = (kt < 8) ? ldfrag(ctxp + am * 256 + kt * 32 + lq * 8)
                           : ldfrag(hb + am * 512 + (kt - 8) * 32 + lq * 8);
          acc = MFMA16(a, WM[kt], acc);
        }
#pragma unroll
        for (int r = 0; r < 4; ++r) {
          int bb = mt * 16 + lq * 4 + r;
          float v = acc[r] + bias;
          if (bn < 80)
            p.out[bb * 5120 + bn * 64 + tau] = v;
          else if (bn == 80)
            p.out[163840 + bb * 64 + tau] = v;
        }
      }
      gbar(p.bar, bid, myg);
      gbar(p.bar, bid, myg);
    }
    // final mel for step 63 (h(64), ctx(63) both ready after last barrier)
    if (act) {
      const int tau = 63;
      const __hip_bfloat16* ctxp = p.ctxb + (tau & 1) * 8192;
      const __hip_bfloat16* hb = p.hbf + ((tau + 1) & 1) * 16384;
      f32x4 acc = {0.f, 0.f, 0.f, 0.f};
#pragma unroll
      for (int kt = 0; kt < 24; ++kt) {
        bf8 a = (kt < 8) ? ldfrag(ctxp + am * 256 + kt * 32 + lq * 8)
                         : ldfrag(hb + am * 512 + (kt - 8) * 32 + lq * 8);
        acc = MFMA16(a, WM[kt], acc);
      }
#pragma unroll
      for (int r = 0; r < 4; ++r) {
        int bb = mt * 16 + lq * 4 + r;
        float v = acc[r] + bias;
        if (bn < 80)
          p.out[bb * 5120 + bn * 64 + tau] = v;
        else if (bn == 80)
          p.out[163840 + bb * 64 + tau] = v;
      }
    }
  }
}

extern "C" void kernel_launch(void* const* d_in, const int* in_sizes, int n_in,
                              void* d_out, int out_size, void* d_ws, size_t ws_size,
                              hipStream_t stream) {
  Params P;
  P.dec = (const float*)d_in[0];
  P.ali = (const float*)d_in[1];
  P.watt = (const float*)d_in[2];
  P.wih = (const float*)d_in[3];
  P.whh = (const float*)d_in[4];
  P.wmel = (const float*)d_in[5];
  P.bmel = (const float*)d_in[6];
  P.wgate = (const float*)d_in[7];
  P.bgate = (const float*)d_in[8];
  P.out = (float*)d_out;

  char* w = (char*)d_ws;
  size_t o = 0;
  auto nxt = [&](size_t b) {
    char* r = w + o;
    o += (b + 255) & ~(size_t)255;
    return r;
  };
  P.bar = (unsigned*)nxt(8192);
  P.wihb = (__hip_bfloat16*)nxt(1536 * 512 * 2);
  P.whhb = (__hip_bfloat16*)nxt(1536 * 512 * 2);
  P.wmelgb = (__hip_bfloat16*)nxt(96 * 768 * 2);
  P.seqb = (__hip_bfloat16*)nxt(64 * 32 * 256 * 2);
  P.hbf = (__hip_bfloat16*)nxt(2 * 32 * 512 * 2);
  P.ctxb = (__hip_bfloat16*)nxt(2 * 32 * 256 * 2);
  P.wattp = (unsigned*)nxt(256 * 256 * 4);
  P.hf = (float*)nxt(32 * 512 * 4);

  (void)hipFuncSetAttribute((const void*)rdec_kernel,
                            hipFuncAttributeMaxDynamicSharedMemorySize, SMEM_BYTES);

  void* args[] = {&P};
  hipError_t err = hipLaunchCooperativeKernel((void*)rdec_kernel, dim3(66), dim3(512),
                                              args, SMEM_BYTES, stream);
  if (err != hipSuccess) {
    // fallback: plain launch (66 blocks on 256 CUs -> trivially co-resident)
    rdec_kernel<<<dim3(66), dim3(512), SMEM_BYTES, stream>>>(P);
  }
}